// Round 14
// baseline (249.508 us; speedup 1.0000x reference)
//
#include <hip/hip_runtime.h>
#include <hip/hip_bf16.h>

#define DIM 8192
#define KSPLIT 16
#define PARTIAL_ELEMS (32 * DIM)   // one fp32 copy of the output per k-chunk
#define MAGIC 0x13579BDFu          // 4 distinct bytes: never equals repeated-byte poison

typedef __bf16 bf16x8 __attribute__((ext_vector_type(8)));
typedef __bf16 bf16x2 __attribute__((ext_vector_type(2)));
typedef float f32x4 __attribute__((ext_vector_type(4)));
typedef float f32x2 __attribute__((ext_vector_type(2)));

// fp32x4 -> bf16x4 (RNE via fptrunc -> packed v_cvt_pk_bf16_f32)
__device__ __forceinline__ uint2 cvt_f4(const float4 v) {
  bf16x2 lo = __builtin_convertvector((f32x2){v.x, v.y}, bf16x2);
  bf16x2 hi = __builtin_convertvector((f32x2){v.z, v.w}, bf16x2);
  uint2 r;
  r.x = __builtin_bit_cast(unsigned, lo);
  r.y = __builtin_bit_cast(unsigned, hi);
  return r;
}

// ---------------------------------------------------------------------------
// ONE dispatch. grid 512 = 32 mc (low 5 bits) x 16 kc; block 512 (8 waves);
// 55.5 KB LDS -> 2 WG/CU -> all 512 WGs co-resident (publish-before-spin +
// full residency = deadlock-free).
//
// Staging + hot loop + partial stores + flag/reduce graft: VERBATIM the R10
// kernel (passed, absmax 0.5 -- correctness proven). ONLY the sync cost model
// changed: R10 polled with __ATOMIC_ACQUIRE, invalidating the poller's L2
// every iteration (512 WGs x kHz polls -> all memory at 218 GB/s, 149 us).
// Fix: RELAXED polls (no cache ops), then ONE acquire fence per thread after
// the flags are observed. Release side unchanged (one fence+release per WG).
// ---------------------------------------------------------------------------
__global__ __launch_bounds__(512, 4)
void bcl_fused_kernel(const float* __restrict__ X,
                      const float* __restrict__ Blk,
                      float* __restrict__ Out,
                      float* __restrict__ Ws,
                      unsigned* __restrict__ Flag) {
  // x: [s:16][b0:2][kh:4][p:16][j:8] bf16 (32 KB): frag = contiguous 1KB
  __shared__ __align__(16) unsigned short Xl[16384];
  // blocks window: 47 slots x 512B, each repacked [qh:2][p:16][j:8]
  __shared__ __align__(16) unsigned short Wl[47 * 256];

  const int tid = threadIdx.x;
  const int mc  = blockIdx.x & 31;
  const int kc  = blockIdx.x >> 5;
  const int kbase = kc * 512;

  // ---- stage x (fp32->bf16). LDS stores linear (conflict-free).
  #pragma unroll
  for (int it = 0; it < 8; ++it) {
    const int L  = (tid + it * 512) << 2;     // elem index in Xl
    const int j4 = L & 7;
    const int p  = (L >> 3) & 15;
    const int kh = (L >> 7) & 3;
    const int b0 = (L >> 9) & 1;
    const int s  = (L >> 10) & 15;
    const int batch = b0 * 16 + p;
    const int kg = kbase + s * 32 + (kh >> 1) * 16 + (kh & 1) * 8 + j4;
    const float4 v = *reinterpret_cast<const float4*>(X + batch * DIM + kg);
    *reinterpret_cast<uint2*>(&Xl[L]) = cvt_f4(v);
  }

  // ---- stage blocks window: slot w holds blocks[(dbase+w)&511] as [qh][p][j]
  const int dbase = (mc * 16 - kc * 32 - 31) & 511;
  for (int i = tid; i < 47 * 64; i += 512) {
    const int w  = i >> 6;
    const int r  = (i & 63) << 2;             // elem in repacked block
    const int qh = r >> 7;
    const int p  = (r >> 3) & 15;
    const int j4 = r & 7;
    const int d  = (dbase + w) & 511;
    const float4 v = *reinterpret_cast<const float4*>(Blk + d * 256 + p * 16 + qh * 8 + j4);
    *reinterpret_cast<uint2*>(&Wl[w * 256 + r]) = cvt_f4(v);
  }

  __syncthreads();   // only compute barrier

  const int lane = tid & 63;
  const int wid  = tid >> 6;                  // 0..7

  // x-frag (a-operand): lane l -> Xl[s*1024 + b0*512 + l*8]
  const unsigned short* Xb = &Xl[lane << 3];
  // blocks-frag (b-operand): lanes 0-31 read slot w0, 32-63 read slot w0-1,
  // each half contiguous 512B; flat = (w0-1)*256 elems + per-lane offset:
  const unsigned short* Wb = &Wl[(((lane >> 5) ^ 1) << 8) + (((lane >> 4) & 1) << 7) + ((lane & 15) << 3)];

  f32x4 acc[2][2];
  #pragma unroll
  for (int t = 0; t < 2; ++t)
    #pragma unroll
    for (int b = 0; b < 2; ++b)
      acc[t][b] = (f32x4){0.f, 0.f, 0.f, 0.f};

  #pragma unroll 4
  for (int s = 0; s < 16; ++s) {
    const bf16x8 x0 = *reinterpret_cast<const bf16x8*>(Xb + (s << 10));
    const bf16x8 x1 = *reinterpret_cast<const bf16x8*>(Xb + (s << 10) + 512);
    #pragma unroll
    for (int t = 0; t < 2; ++t) {
      const int mt = (wid << 1) + t;          // 0..15
      const bf16x8 wf = *reinterpret_cast<const bf16x8*>(Wb + ((mt + 30 - 2 * s) << 8));
      acc[t][0] = __builtin_amdgcn_mfma_f32_16x16x32_bf16(x0, wf, acc[t][0], 0, 0, 0);
      acc[t][1] = __builtin_amdgcn_mfma_f32_16x16x32_bf16(x1, wf, acc[t][1], 0, 0, 0);
    }
  }

  // ---- partial store: C/D layout col=lane&15 (=p), row=(lane>>4)*4+reg.
  // Plain streaming stores: 4 rows x 16 contiguous cols per inst (64B segments).
  float* base = Ws + (size_t)kc * PARTIAL_ELEMS + mc * 256;
  #pragma unroll
  for (int t = 0; t < 2; ++t) {
    const int col = ((wid << 1) + t) * 16 + (lane & 15);
    #pragma unroll
    for (int b0 = 0; b0 < 2; ++b0) {
      const int brow = b0 * 16 + ((lane >> 4) << 2);
      #pragma unroll
      for (int r = 0; r < 4; ++r)
        base[(brow + r) * DIM + col] = acc[t][b0][r];
    }
  }

  // ---- publish (release), then wait for this mc's 16 partials (RELAXED
  // polls -- no per-poll cache invalidation; that was R10's 149us bug),
  // then ONE acquire fence before reading partials.
  __threadfence();                 // release: partials -> coherence point
  __syncthreads();                 // all threads' stores+fence precede publish
  if (tid == 0)
    __hip_atomic_store(&Flag[(mc << 4) + kc], MAGIC,
                       __ATOMIC_RELEASE, __HIP_MEMORY_SCOPE_AGENT);
  if (tid < 16) {
    while (__hip_atomic_load(&Flag[(mc << 4) + tid],
                             __ATOMIC_RELAXED, __HIP_MEMORY_SCOPE_AGENT) != MAGIC)
      __builtin_amdgcn_s_sleep(2);
  }
  __syncthreads();
  __threadfence();                 // acquire: flags observed -> partials visible

  // ---- distributed reduction: this WG owns cols [mc*256 + kc*16, +16),
  // all 32 rows = 512 elems = 1 per thread. Fixed kc order -> deterministic.
  const int row = tid >> 4;                    // 0..31
  const int col = mc * 256 + (kc << 4) + (tid & 15);
  const float* p = Ws + row * DIM + col;
  float a = p[0];
  #pragma unroll
  for (int k = 1; k < KSPLIT; ++k) a += p[(size_t)k * PARTIAL_ELEMS];
  Out[row * DIM + col] = a;
}

extern "C" void kernel_launch(void* const* d_in, const int* in_sizes, int n_in,
                              void* d_out, int out_size, void* d_ws, size_t ws_size,
                              hipStream_t stream) {
  const float* X   = (const float*)d_in[0];   // [32, 8192] fp32
  const float* Blk = (const float*)d_in[1];   // [512, 16, 16] fp32
  float* Out = (float*)d_out;                 // [32, 8192] fp32
  unsigned* Flag = (unsigned*)d_ws;           // 512 flags (2 KB), re-poisoned each iter
  float* Ws  = (float*)((char*)d_ws + 4096);  // 16 MB fp32 partials

  bcl_fused_kernel<<<dim3(512), dim3(512), 0, stream>>>(X, Blk, Out, Ws, Flag);
}

// Round 18
// 224.468 us; speedup vs baseline: 1.1116x; 1.1116x over previous
//
#include <hip/hip_runtime.h>
#include <hip/hip_bf16.h>

#define DIM 8192
#define KSPLIT 16
#define PARTIAL_ELEMS (32 * DIM)   // one fp32 copy of the output per k-chunk

typedef __bf16 bf16x8 __attribute__((ext_vector_type(8)));
typedef __bf16 bf16x2 __attribute__((ext_vector_type(2)));
typedef float f32x4 __attribute__((ext_vector_type(4)));
typedef float f32x2 __attribute__((ext_vector_type(2)));

// fp32x4 -> bf16x4 (RNE via fptrunc -> packed v_cvt_pk_bf16_f32)
__device__ __forceinline__ uint2 cvt_f4(const float4 v) {
  bf16x2 lo = __builtin_convertvector((f32x2){v.x, v.y}, bf16x2);
  bf16x2 hi = __builtin_convertvector((f32x2){v.z, v.w}, bf16x2);
  uint2 r;
  r.x = __builtin_bit_cast(unsigned, lo);
  r.y = __builtin_bit_cast(unsigned, hi);
  return r;
}

// ---------------------------------------------------------------------------
// ONE dispatch, NO polling. grid 512 = 32 mc x 16 kc; block 512 (8 waves).
// Staging + hot loop + partial stores: VERBATIM the measured-good R1 code.
//
// Combine = LAST-ARRIVER fixup (poll-free):
//  R10 lesson: acquire-polls invalidate the poller's L2 each poll -> 149us.
//  R14 lesson: relaxed-polls can hit a stale (non-coherent) L2 line forever
//  -> 198us. Atomic RMWs avoid both: they execute at the coherence point
//  (never stale) and don't invalidate the issuer's L2 (no storm).
//  Each WG: store partials -> release fence -> 4x fetch_add on quarter
//  counters; the return value identifies the unique 16th arriver per
//  (mc, quarter). Non-last WGs EXIT. Last arriver acquires once and reduces
//  its disjoint 32x64 slice in fixed kc order (deterministic).
//  Counters live in poisoned ws: detection is RELATIVE -- baseline poison is
//  read from untouched mirror slots (fill = repeated-dword pattern, rewritten
//  every iteration), so old - baseline == 15 works for any poison value.
// ---------------------------------------------------------------------------
__global__ __launch_bounds__(512, 4)
void bcl_fused_kernel(const float* __restrict__ X,
                      const float* __restrict__ Blk,
                      float* __restrict__ Out,
                      float* __restrict__ Ws,
                      unsigned* __restrict__ Cnt) {
  // x: [s:16][b0:2][kh:4][p:16][j:8] bf16 (32 KB): frag = contiguous 1KB
  __shared__ __align__(16) unsigned short Xl[16384];
  // blocks window: 47 slots x 512B, each repacked [qh:2][p:16][j:8]
  __shared__ __align__(16) unsigned short Wl[47 * 256];
  __shared__ unsigned lastmask;

  const int tid = threadIdx.x;
  const int mc  = blockIdx.x & 31;
  const int kc  = blockIdx.x >> 5;
  const int kbase = kc * 512;

  // ---- stage x (fp32->bf16). LDS stores linear (conflict-free).
  #pragma unroll
  for (int it = 0; it < 8; ++it) {
    const int L  = (tid + it * 512) << 2;     // elem index in Xl
    const int j4 = L & 7;
    const int p  = (L >> 3) & 15;
    const int kh = (L >> 7) & 3;
    const int b0 = (L >> 9) & 1;
    const int s  = (L >> 10) & 15;
    const int batch = b0 * 16 + p;
    const int kg = kbase + s * 32 + (kh >> 1) * 16 + (kh & 1) * 8 + j4;
    const float4 v = *reinterpret_cast<const float4*>(X + batch * DIM + kg);
    *reinterpret_cast<uint2*>(&Xl[L]) = cvt_f4(v);
  }

  // ---- stage blocks window: slot w holds blocks[(dbase+w)&511] as [qh][p][j]
  const int dbase = (mc * 16 - kc * 32 - 31) & 511;
  for (int i = tid; i < 47 * 64; i += 512) {
    const int w  = i >> 6;
    const int r  = (i & 63) << 2;             // elem in repacked block
    const int qh = r >> 7;
    const int p  = (r >> 3) & 15;
    const int j4 = r & 7;
    const int d  = (dbase + w) & 511;
    const float4 v = *reinterpret_cast<const float4*>(Blk + d * 256 + p * 16 + qh * 8 + j4);
    *reinterpret_cast<uint2*>(&Wl[w * 256 + r]) = cvt_f4(v);
  }

  __syncthreads();   // only compute barrier

  const int lane = tid & 63;
  const int wid  = tid >> 6;                  // 0..7

  // x-frag (a-operand): lane l -> Xl[s*1024 + b0*512 + l*8]
  const unsigned short* Xb = &Xl[lane << 3];
  // blocks-frag (b-operand): lanes 0-31 read slot w0, 32-63 read slot w0-1,
  // each half contiguous 512B; flat = (w0-1)*256 elems + per-lane offset:
  const unsigned short* Wb = &Wl[(((lane >> 5) ^ 1) << 8) + (((lane >> 4) & 1) << 7) + ((lane & 15) << 3)];

  f32x4 acc[2][2];
  #pragma unroll
  for (int t = 0; t < 2; ++t)
    #pragma unroll
    for (int b = 0; b < 2; ++b)
      acc[t][b] = (f32x4){0.f, 0.f, 0.f, 0.f};

  #pragma unroll 4
  for (int s = 0; s < 16; ++s) {
    const bf16x8 x0 = *reinterpret_cast<const bf16x8*>(Xb + (s << 10));
    const bf16x8 x1 = *reinterpret_cast<const bf16x8*>(Xb + (s << 10) + 512);
    #pragma unroll
    for (int t = 0; t < 2; ++t) {
      const int mt = (wid << 1) + t;          // 0..15
      const bf16x8 wf = *reinterpret_cast<const bf16x8*>(Wb + ((mt + 30 - 2 * s) << 8));
      acc[t][0] = __builtin_amdgcn_mfma_f32_16x16x32_bf16(x0, wf, acc[t][0], 0, 0, 0);
      acc[t][1] = __builtin_amdgcn_mfma_f32_16x16x32_bf16(x1, wf, acc[t][1], 0, 0, 0);
    }
  }

  // ---- partial store: C/D layout col=lane&15 (=p), row=(lane>>4)*4+reg.
  // Plain streaming stores: 4 rows x 16 contiguous cols per inst (64B segments).
  float* base = Ws + (size_t)kc * PARTIAL_ELEMS + mc * 256;
  #pragma unroll
  for (int t = 0; t < 2; ++t) {
    const int col = ((wid << 1) + t) * 16 + (lane & 15);
    #pragma unroll
    for (int b0 = 0; b0 < 2; ++b0) {
      const int brow = b0 * 16 + ((lane >> 4) << 2);
      #pragma unroll
      for (int r = 0; r < 4; ++r)
        base[(brow + r) * DIM + col] = acc[t][b0][r];
    }
  }

  // ---- last-arriver detection (poll-free)
  __threadfence();                 // release: partials -> coherence point
  __syncthreads();                 // all threads' stores+fence precede RMW
  if (tid == 0) {
    unsigned m = 0;
    #pragma unroll
    for (int q = 0; q < 4; ++q) {
      const unsigned pbase = Cnt[256 + (mc << 2) + q];   // untouched poison mirror
      const unsigned old = __hip_atomic_fetch_add(&Cnt[(mc << 2) + q], 1u,
                               __ATOMIC_ACQ_REL, __HIP_MEMORY_SCOPE_AGENT);
      if (old - pbase == 15u) m |= (1u << q);
    }
    lastmask = m;
  }
  __syncthreads();
  const unsigned m = lastmask;
  if (m == 0) return;              // 480 WGs exit immediately; no waiting
  __threadfence();                 // acquire: others' partials now visible

  // ---- fixup: reduce owned quarter(s): 32 rows x 64 cols, fixed kc order.
  #pragma unroll
  for (int q = 0; q < 4; ++q) {
    if (!(m & (1u << q))) continue;
    const int cbase = mc * 256 + (q << 6);
    #pragma unroll
    for (int i = 0; i < 4; ++i) {
      const int o   = tid + i * 512;          // 0..2047
      const int row = o >> 6;                 // 0..31
      const int col = cbase + (o & 63);
      const float* p = Ws + row * DIM + col;
      float a = p[0];
      #pragma unroll
      for (int k = 1; k < KSPLIT; ++k) a += p[(size_t)k * PARTIAL_ELEMS];
      Out[row * DIM + col] = a;
    }
  }
}

extern "C" void kernel_launch(void* const* d_in, const int* in_sizes, int n_in,
                              void* d_out, int out_size, void* d_ws, size_t ws_size,
                              hipStream_t stream) {
  const float* X   = (const float*)d_in[0];   // [32, 8192] fp32
  const float* Blk = (const float*)d_in[1];   // [512, 16, 16] fp32
  float* Out = (float*)d_out;                 // [32, 8192] fp32
  float* Ws  = (float*)d_ws;                  // 16 MB fp32 partials
  // counters: 128 used + mirror poison reads at [256..384); re-poisoned each iter
  unsigned* Cnt = (unsigned*)((char*)d_ws + (size_t)KSPLIT * PARTIAL_ELEMS * 4);

  bcl_fused_kernel<<<dim3(512), dim3(512), 0, stream>>>(X, Blk, Out, Ws, Cnt);
}

// Round 21
// 77.221 us; speedup vs baseline: 3.2311x; 2.9068x over previous
//
#include <hip/hip_runtime.h>
#include <hip/hip_bf16.h>

#define DIM 8192
#define KSPLIT 32
#define PARTIAL_ELEMS (32 * DIM)   // one fp32 copy of the output per k-chunk

typedef __bf16 bf16x8 __attribute__((ext_vector_type(8)));
typedef __bf16 bf16x2 __attribute__((ext_vector_type(2)));
typedef float f32x4 __attribute__((ext_vector_type(4)));
typedef float f32x2 __attribute__((ext_vector_type(2)));

// fp32x4 -> bf16x4 (RNE via fptrunc -> packed v_cvt_pk_bf16_f32)
__device__ __forceinline__ uint2 cvt_f4(const float4 v) {
  bf16x2 lo = __builtin_convertvector((f32x2){v.x, v.y}, bf16x2);
  bf16x2 hi = __builtin_convertvector((f32x2){v.z, v.w}, bf16x2);
  uint2 r;
  r.x = __builtin_bit_cast(unsigned, lo);
  r.y = __builtin_bit_cast(unsigned, hi);
  return r;
}

// ---------------------------------------------------------------------------
// REVERSION + occupancy attack. In-kernel cross-WG combines are dead on this
// chip (measured: atomics 61us R6, acquire-poll 149us R10, relaxed-poll 198us
// R14, last-arriver RMW 171us R18 -- the kernel boundary at ~4us/dispatch is
// the cheapest cross-XCD coherence op). Structure = R1's measured-best 70.7us
// two-dispatch pipeline, with ONE delta: KSPLIT 16->32.
//   K/WG 512->256  => Xl 32->16 KB, window 47->32 slots (16 KB)
//   => LDS 55.5->32 KB => 2->4 WG/CU (32 waves/CU, max) and per-WG staging
//   halves. Slot algebra identical with 32->16: dbase=mc*16-kc*16-15,
//   slot=mt+14-2s (+1 for lanes<32), max slot 30 < 32 staged.
// Cost: Ws 16->32 MB (reduce reads 2x, LLC-resident).
// ---------------------------------------------------------------------------
__global__ __launch_bounds__(512, 8)
void bcl_mfma_kernel(const float* __restrict__ X,
                     const float* __restrict__ Blk,
                     float* __restrict__ Ws) {
  // x: [s:8][b0:2][kh:4][p:16][j:8] bf16 (16 KB): frag = contiguous 1KB
  __shared__ __align__(16) unsigned short Xl[8192];
  // blocks window: 32 slots x 512B, each repacked [qh:2][p:16][j:8] (16 KB)
  __shared__ __align__(16) unsigned short Wl[32 * 256];

  const int tid = threadIdx.x;
  const int mc  = blockIdx.x & 31;
  const int kc  = blockIdx.x >> 5;            // 0..31
  const int kbase = kc * 256;

  // ---- stage x (fp32->bf16). LDS stores linear (conflict-free).
  #pragma unroll
  for (int it = 0; it < 4; ++it) {
    const int L  = (tid + it * 512) << 2;     // elem index in Xl (< 8192)
    const int j4 = L & 7;
    const int p  = (L >> 3) & 15;
    const int kh = (L >> 7) & 3;
    const int b0 = (L >> 9) & 1;
    const int s  = (L >> 10) & 7;
    const int batch = b0 * 16 + p;
    const int kg = kbase + s * 32 + (kh >> 1) * 16 + (kh & 1) * 8 + j4;
    const float4 v = *reinterpret_cast<const float4*>(X + batch * DIM + kg);
    *reinterpret_cast<uint2*>(&Xl[L]) = cvt_f4(v);
  }

  // ---- stage blocks window: slot w holds blocks[(dbase+w)&511] as [qh][p][j]
  const int dbase = (mc * 16 - kc * 16 - 15) & 511;
  #pragma unroll
  for (int it = 0; it < 4; ++it) {
    const int i  = tid + it * 512;            // < 2048
    const int w  = i >> 6;                    // slot 0..31
    const int r  = (i & 63) << 2;             // elem in repacked block
    const int qh = r >> 7;
    const int p  = (r >> 3) & 15;
    const int j4 = r & 7;
    const int d  = (dbase + w) & 511;
    const float4 v = *reinterpret_cast<const float4*>(Blk + d * 256 + p * 16 + qh * 8 + j4);
    *reinterpret_cast<uint2*>(&Wl[w * 256 + r]) = cvt_f4(v);
  }

  __syncthreads();   // only barrier

  const int lane = tid & 63;
  const int wid  = tid >> 6;                  // 0..7

  // x-frag (a-operand): lane l -> Xl[s*1024 + b0*512 + l*8]
  const unsigned short* Xb = &Xl[lane << 3];
  // blocks-frag (b-operand): lanes 0-31 read slot w0+1, 32-63 read slot w0,
  // each half contiguous 512B (verified R1 layout, window offset 30->14):
  const unsigned short* Wb = &Wl[(((lane >> 5) ^ 1) << 8) + (((lane >> 4) & 1) << 7) + ((lane & 15) << 3)];

  f32x4 acc[2][2];
  #pragma unroll
  for (int t = 0; t < 2; ++t)
    #pragma unroll
    for (int b = 0; b < 2; ++b)
      acc[t][b] = (f32x4){0.f, 0.f, 0.f, 0.f};

  #pragma unroll
  for (int s = 0; s < 8; ++s) {
    const bf16x8 x0 = *reinterpret_cast<const bf16x8*>(Xb + (s << 10));
    const bf16x8 x1 = *reinterpret_cast<const bf16x8*>(Xb + (s << 10) + 512);
    #pragma unroll
    for (int t = 0; t < 2; ++t) {
      const int mt = (wid << 1) + t;          // 0..15
      const bf16x8 wf = *reinterpret_cast<const bf16x8*>(Wb + ((mt + 14 - 2 * s) << 8));
      acc[t][0] = __builtin_amdgcn_mfma_f32_16x16x32_bf16(x0, wf, acc[t][0], 0, 0, 0);
      acc[t][1] = __builtin_amdgcn_mfma_f32_16x16x32_bf16(x1, wf, acc[t][1], 0, 0, 0);
    }
  }

  // ---- epilogue: C/D layout col=lane&15 (=p), row=(lane>>4)*4+reg.
  // Plain streaming stores: 4 rows x 16 contiguous cols per inst (64B segments).
  float* base = Ws + (size_t)kc * PARTIAL_ELEMS + mc * 256;
  #pragma unroll
  for (int t = 0; t < 2; ++t) {
    const int col = ((wid << 1) + t) * 16 + (lane & 15);
    #pragma unroll
    for (int b0 = 0; b0 < 2; ++b0) {
      const int brow = b0 * 16 + ((lane >> 4) << 2);
      #pragma unroll
      for (int r = 0; r < 4; ++r)
        base[(brow + r) * DIM + col] = acc[t][b0][r];
    }
  }
}

// Phase 2: Out = sum of KSPLIT partials. 512 wgs x 256 thr, float2 each
// (R1's measured form). 32 MB read, LLC-resident.
__global__ __launch_bounds__(256)
void bcl_reduce_kernel(const float2* __restrict__ Ws, float2* __restrict__ Out) {
  const int f = blockIdx.x * 256 + threadIdx.x;
  float2 a = Ws[f];
  #pragma unroll
  for (int kc = 1; kc < KSPLIT; ++kc) {
    const float2 v = Ws[kc * (PARTIAL_ELEMS / 2) + f];
    a.x += v.x; a.y += v.y;
  }
  Out[f] = a;
}

extern "C" void kernel_launch(void* const* d_in, const int* in_sizes, int n_in,
                              void* d_out, int out_size, void* d_ws, size_t ws_size,
                              hipStream_t stream) {
  const float* X   = (const float*)d_in[0];   // [32, 8192] fp32
  const float* Blk = (const float*)d_in[1];   // [512, 16, 16] fp32
  float* Ws  = (float*)d_ws;                  // 32 MB fp32 partials
  float* Out = (float*)d_out;                 // [32, 8192] fp32

  bcl_mfma_kernel<<<dim3(1024), dim3(512), 0, stream>>>(X, Blk, Ws);
  bcl_reduce_kernel<<<dim3(PARTIAL_ELEMS / 2 / 256), dim3(256), 0, stream>>>(
      (const float2*)Ws, (float2*)Out);
}